// Round 6
// baseline (155.218 us; speedup 1.0000x reference)
//
#include <hip/hip_runtime.h>

// Problem constants (fixed by reference setup_inputs)
#define BATCH 8
#define NPTS  4096   // N == M == 4096
#define KD    64
#define MQ    4      // m-strips: each block walks 1024 cols = 8 tiles of 128
#define WALK  8
#define FINF  3.0e38f

typedef float f32x4 __attribute__((ext_vector_type(4)));
typedef float f32x2 __attribute__((ext_vector_type(2)));
typedef short s16x8 __attribute__((ext_vector_type(8)));

__device__ __forceinline__ unsigned int f2bf(float f) {
  // round-to-nearest-even fp32 -> bf16 (inputs finite)
  unsigned int u = __float_as_uint(f);
  u += 0x7FFFu + ((u >> 16) & 1u);
  return u >> 16;
}

__device__ __forceinline__ void stage16(const void* g, void* l) {
  // async global->LDS, 16B/lane; LDS dst = wave-uniform base + lane*16
  __builtin_amdgcn_global_load_lds((const __attribute__((address_space(1))) void*)g,
                                   (__attribute__((address_space(3))) void*)l, 16, 0, 0);
}

// Guaranteed 3-input min (verified correct in an earlier round; clean -7
// VALU and -3 dep levels on the 16-wide col-min tree).
__device__ __forceinline__ float min3f(float a, float b, float c) {
  float d;
  asm("v_min3_f32 %0, %1, %2, %3" : "=v"(d) : "v"(a), "v"(b), "v"(c));
  return d;
}

// ---------------------------------------------------------------------------
// Prepass: convert X,Y (fp32 [32768][64]) to bf16 packed (uint [32768][32])
// and compute exact fp32 squared norms. 32 threads per row, 2 floats/thread.
// Also zeroes the completion-ticket counter and +inf-inits the rowmin/colmin
// atomic buffers (stream order makes this race-free).
__global__ __launch_bounds__(256)
void prep_kernel(const float* __restrict__ X, const float* __restrict__ Y,
                 unsigned int* __restrict__ Xbf, unsigned int* __restrict__ Ybf,
                 float* __restrict__ x2, float* __restrict__ y2,
                 unsigned int* __restrict__ minbuf,   // rowmin[32K] | colmin[32K]
                 unsigned int* __restrict__ counter) {
  int gid = blockIdx.x * 256 + threadIdx.x;
  if (gid == 0) *counter = 0;
  if (gid < 2 * BATCH * NPTS) minbuf[gid] = 0x7F800000u;  // +inf (uint-ordered)
  int row = gid >> 5;
  int ki  = gid & 31;
  bool isX = row < BATCH * NPTS;
  int r2 = row & (BATCH * NPTS - 1);
  const float* src = isX ? X : Y;
  f32x2 v = *(const f32x2*)(src + (size_t)r2 * KD + ki * 2);
  float s = v[0] * v[0] + v[1] * v[1];
  #pragma unroll
  for (int m = 16; m >= 1; m >>= 1) s += __shfl_xor(s, m, 64);  // stays in 32-lane half
  unsigned int packed = (f2bf(v[1]) << 16) | f2bf(v[0]);
  (isX ? Xbf : Ybf)[r2 * 32 + ki] = packed;
  if (ki == 0) (isX ? x2 : y2)[r2] = s;
}

// ---------------------------------------------------------------------------
// Main + fused finalize: 1024 blocks, 1D grid with XCD<->batch affinity
// swizzle (b = lin&7 -> batch working set lives in one private L2).
// Block work: 128 rows x 1024 cols (8 m-tiles of 128), waves 2x2, wave tile
// 64x64. X fragments gathered straight from global (L2-hot, once/block);
// LDS = Y double-buffer 32KB + credq/redf ~5KB -> 4 blocks/CU (38KB).
// Min-partials out via clamped uint atomicMin (exact: float-as-uint ordering
// is monotone for non-negative floats; clamp∘min = min∘clamp).
// FUSED REDUCE: after its final atomicMin each block fences and takes a
// device-scope ticket (the same proven pattern the old standalone reduce
// used); ticket 1023 — all mins published — runs the 256KB sqrt-mean with
// return-atomics as device-scope loads and writes the scalar output. This
// removes one dispatch node + launch gap from the graph.
// tt-loop stays `#pragma unroll 2` (full 8x unroll spilled: 528MB scratch).
// launch_bounds(256,2): 128 VGPR — exactly the 4-blocks/CU cap.
__global__ __launch_bounds__(256, 2)
void chamfer_main(const unsigned short* __restrict__ Xbf,
                  const unsigned short* __restrict__ Ybf,
                  const float* __restrict__ x2g, const float* __restrict__ y2g,
                  unsigned int* __restrict__ rowmin,   // [B*N] min over cols (sq, clamped)
                  unsigned int* __restrict__ colmin,   // [B*M] min over rows (sq, clamped)
                  unsigned int* __restrict__ counter,
                  float* __restrict__ out) {
  __shared__ __align__(16) unsigned short Ys[2][128 * 64];   // 32 KB
  __shared__ float l_credq[2 * 4 * 132];                     // 4.1 KB, +4 pad vs banks
  __shared__ float l_redf[256];                              // 1 KB
  __shared__ unsigned int s_ticket;

  const int lin = blockIdx.x;                       // hw id; XCD = lin & 7
  const int logical = (lin & 7) * 128 + (lin >> 3); // bijective (1024 = 8*128)
  const int mq = logical & 3, ntile = (logical >> 2) & 31, b = logical >> 7;
  const int n0 = ntile * 128;
  const int mbase = mq * (WALK * 128);
  const int t = threadIdx.x, w = t >> 6, lane = t & 63, c = lane & 15, q = lane >> 4;
  const int wr = (w >> 1) * 64, wc = (w & 1) * 64, rg = w >> 1;

  // staging source offset within a 1KB (8-row) block: row=lane>>3, chunk=(lane&7)^(lane>>3)
  const int l8 = lane >> 3;
  const int lane_off = l8 * 128 + (((lane & 7) ^ l8) << 4);

  const unsigned short* Xrow = Xbf + (size_t)(b * NPTS + n0) * KD;  // [128][64] bf16
  const char* Yg0 = (const char*)(Ybf + (size_t)(b * NPTS + mbase) * KD);

  // Prologue: stage Y tile 0 (4 x 1KB per wave)
  #pragma unroll
  for (int k = 0; k < 4; ++k)
    stage16(Yg0 + (k * 32 + w * 8) * 128 + lane_off,
            (char*)Ys[0] + (k * 256 + w * 64) * 16);

  // X fragments straight from global (once per block). Lane (q,c) reads rows
  // wr+i*16+c, k-chunk (ks*4+q)*8 — per instr: 16 rows x 64B segments. 32 VGPRs.
  s16x8 xf[4][2];
  #pragma unroll
  for (int i = 0; i < 4; ++i)
    #pragma unroll
    for (int ks = 0; ks < 2; ++ks)
      xf[i][ks] = *(const s16x8*)&Xrow[(size_t)(wr + i * 16 + c) * KD + (ks * 4 + q) * 8];

  // x2 fragment (rows wr + i*16 + q*4 + r), fp32, L2-hot. 16 VGPRs.
  const float* x2b = x2g + b * NPTS + n0;
  f32x4 x2r[4];
  #pragma unroll
  for (int i = 0; i < 4; ++i) x2r[i] = *(const f32x4*)(x2b + wr + i * 16 + q * 4);

  __syncthreads();  // drains the Y0 global_load_lds (vmcnt 0 at barrier)

  float rm[4][4];
  #pragma unroll
  for (int i = 0; i < 4; ++i)
    #pragma unroll
    for (int r = 0; r < 4; ++r) rm[i][r] = FINF;

  const int cx = c & 7;
  const float* y2b = y2g + b * NPTS + mbase;
  unsigned int* colbase = colmin + (size_t)b * NPTS + mbase;
  const f32x4 zacc = {0.f, 0.f, 0.f, 0.f};

  #pragma unroll 2
  for (int tt = 0; tt < WALK; ++tt) {
    const unsigned short* cur = Ys[tt & 1];

    // y2 for this wave's 4 col groups — issue global loads first (async).
    float y2c[4];
    #pragma unroll
    for (int j = 0; j < 4; ++j) y2c[j] = y2b[tt * 128 + wc + j * 16 + c];

    if (tt < WALK - 1) {  // async-prefetch next Y tile into the other buffer
      const char* Ygt = Yg0 + (size_t)(tt + 1) * 128 * 128;
      unsigned short* nb = Ys[(tt + 1) & 1];
      #pragma unroll
      for (int k = 0; k < 4; ++k)
        stage16(Ygt + (k * 32 + w * 8) * 128 + lane_off,
                (char*)nb + (k * 256 + w * 64) * 16);
    }

    // Flush previous tile's col-mins: combine 4 q-pair/rowgroup partials,
    // add y2, clamp, atomicMin (L2-local: all writers share XCD b).
    if (tt > 0 && t < 128) {
      int pt = tt - 1, pb = pt & 1;
      float v = fminf(fminf(l_credq[(pb * 4 + 0) * 132 + t], l_credq[(pb * 4 + 1) * 132 + t]),
                      fminf(l_credq[(pb * 4 + 2) * 132 + t], l_credq[(pb * 4 + 3) * 132 + t]));
      float d = fmaxf(v + y2b[pt * 128 + t], 0.f);
      atomicMin(&colbase[pt * 128 + t], __float_as_uint(d));
    }

    float cmj[4];
    #pragma unroll
    for (int j = 0; j < 4; ++j) {
      const unsigned short* yrow = &cur[(wc + j * 16 + c) * 64];
      s16x8 yf0 = *(const s16x8*)&yrow[(q ^ cx) << 3];
      s16x8 yf1 = *(const s16x8*)&yrow[((4 + q) ^ cx) << 3];
      f32x4 acc[4];
      #pragma unroll
      for (int i = 0; i < 4; ++i) {
        f32x4 a0 = __builtin_amdgcn_mfma_f32_16x16x32_bf16(xf[i][0], yf0, zacc, 0, 0, 0);
        acc[i] = __builtin_amdgcn_mfma_f32_16x16x32_bf16(xf[i][1], yf1, a0, 0, 0, 0);
      }
      // Epilogue: rm path (y2 - 2v) and col path u = (x2 - 2v).
      float u[16];  // all indices compile-time (stays in VGPRs)
      #pragma unroll
      for (int i = 0; i < 4; ++i)
        #pragma unroll
        for (int r = 0; r < 4; ++r) {
          float v = acc[i][r];
          rm[i][r] = fminf(rm[i][r], fmaf(-2.f, v, y2c[j]));
          u[i * 4 + r] = fmaf(-2.f, v, x2r[i][r]);
        }
      // col-min over this lane's 16 row values: depth-3 min3 tree (8 ops)
      float c0 = min3f(u[0],  u[1],  u[2]);
      float c1 = min3f(u[3],  u[4],  u[5]);
      float c2 = min3f(u[6],  u[7],  u[8]);
      float c3 = min3f(u[9],  u[10], u[11]);
      float c4 = min3f(u[12], u[13], u[14]);
      float c5 = min3f(c0, c1, u[15]);
      float cm = fminf(min3f(c2, c3, c4), c5);
      // ONE cross-lane step: combine q-pairs {0,1} and {2,3}
      cm = fminf(cm, __shfl_xor(cm, 16, 64));
      cmj[j] = cm;
    }
    // Each lane stores 2 of the (q-half, j) partials: q&1 picks the j-pair,
    // q>>1 picks the row-half slot. Addr stride 132 breaks the x128 bank alias.
    {
      int s = rg * 2 + (q >> 1);
      int jA = (q & 1) * 2;
      float sA = (q & 1) ? cmj[2] : cmj[0];
      float sB = (q & 1) ? cmj[3] : cmj[1];
      float* dst = &l_credq[((tt & 1) * 4 + s) * 132 + wc + c];
      dst[jA * 16]      = sA;
      dst[jA * 16 + 16] = sB;
    }

    __syncthreads();  // buffer swap barrier (prefetch had MFMA+epilogue to land)
  }

  // Row-min: reduce over the 16 c-lanes within each q-group...
  #pragma unroll
  for (int msk = 1; msk <= 8; msk <<= 1)
    #pragma unroll
    for (int i = 0; i < 4; ++i)
      #pragma unroll
      for (int r = 0; r < 4; ++r)
        rm[i][r] = fminf(rm[i][r], __shfl_xor(rm[i][r], msk, 64));
  // ...then store per-wave row-mins to LDS (literal indices only).
  if (c == 0) {
    #pragma unroll
    for (int i = 0; i < 4; ++i) {
      f32x4 v = {rm[i][0], rm[i][1], rm[i][2], rm[i][3]};
      *(f32x4*)&l_redf[w * 64 + i * 16 + q * 4] = v;
    }
  }
  __syncthreads();

  if (t < 128) {
    // flush the final tile's col-mins (last loop barrier made them visible)
    {
      int pt = WALK - 1, pb = pt & 1;
      float v = fminf(fminf(l_credq[(pb * 4 + 0) * 132 + t], l_credq[(pb * 4 + 1) * 132 + t]),
                      fminf(l_credq[(pb * 4 + 2) * 132 + t], l_credq[(pb * 4 + 3) * 132 + t]));
      float d = fmaxf(v + y2b[pt * 128 + t], 0.f);
      atomicMin(&colbase[pt * 128 + t], __float_as_uint(d));
    }
    // combine the 2 col-group waves of each row group, add x2, clamp, atomicMin
    int g = t >> 6, lr = t & 63;
    float v = fminf(l_redf[(g * 2) * 64 + lr], l_redf[(g * 2 + 1) * 64 + lr]) + x2b[t];
    atomicMin(&rowmin[(size_t)b * NPTS + n0 + t], __float_as_uint(fmaxf(v, 0.f)));
  }

  // ---- Fused finalize (ticket pattern identical to the proven standalone
  // reduce): syncthreads drains this block's atomics (vmcnt 0 at barrier);
  // thread 0 fences + takes a device-scope ticket. The block drawing 1023
  // sees all 1024 blocks' device-scope atomicMins complete.
  __syncthreads();
  if (t == 0) {
    __threadfence();
    s_ticket = atomicAdd(counter, 1);
  }
  __syncthreads();
  if (s_ticket == MQ * 32 * BATCH - 1) {
    const int TOT = BATCH * NPTS;
    float s0 = 0.f;
    for (int i = t; i < TOT; i += 256) {
      // return-atomics as device-scope loads (min with UINT_MAX = no-op)
      unsigned int rv = atomicMin(&rowmin[i], 0xFFFFFFFFu);
      unsigned int cv = atomicMin(&colmin[i], 0xFFFFFFFFu);
      s0 += sqrtf(__uint_as_float(rv)) + sqrtf(__uint_as_float(cv));
    }
    #pragma unroll
    for (int m = 32; m >= 1; m >>= 1) s0 += __shfl_xor(s0, m, 64);
    if (lane == 0) l_redf[w] = s0;
    __syncthreads();
    if (t == 0)
      out[0] = (l_redf[0] + l_redf[1] + l_redf[2] + l_redf[3]) * (1.0f / (float)TOT);
  }
}

// ---------------------------------------------------------------------------
extern "C" void kernel_launch(void* const* d_in, const int* in_sizes, int n_in,
                              void* d_out, int out_size, void* d_ws, size_t ws_size,
                              hipStream_t stream) {
  const float* X = (const float*)d_in[0];  // [B, N, 64] fp32
  const float* Y = (const float*)d_in[1];  // [B, M, 64] fp32
  float* out = (float*)d_out;

  // Workspace layout (bytes):
  //   Xbf 4MB | Ybf 4MB | x2 128KB | y2 128KB | rowmin 128KB | colmin 128KB
  //   | counter 4B
  char* ws = (char*)d_ws;
  unsigned int* Xbf = (unsigned int*)ws;                       // packed bf16 pairs
  unsigned int* Ybf = (unsigned int*)(ws + (4u << 20));
  float* x2 = (float*)(ws + (8u << 20));
  float* y2 = (float*)(ws + (8u << 20) + (128u << 10));
  unsigned int* minbuf = (unsigned int*)(ws + (8u << 20) + (256u << 10));
  unsigned int* rowmin = minbuf;                               // [32768]
  unsigned int* colmin = minbuf + BATCH * NPTS;                // [32768]
  unsigned int* counter = (unsigned int*)(ws + (8u << 20) + (512u << 10));

  // Prepass: both inputs, 32 threads/row. Also zeroes `counter` and
  // +inf-inits rowmin/colmin.
  prep_kernel<<<dim3(2 * BATCH * NPTS * 32 / 256), dim3(256), 0, stream>>>(
      X, Y, Xbf, Ybf, x2, y2, minbuf, counter);

  // Main + fused finalize: 1024 blocks 1D (XCD swizzle decoded in-kernel),
  // 4 resident/CU. Last-finishing block writes the scalar output.
  chamfer_main<<<dim3(MQ * 32 * BATCH), dim3(256), 0, stream>>>(
      (const unsigned short*)Xbf, (const unsigned short*)Ybf, x2, y2,
      rowmin, colmin, counter, out);
}

// Round 7
// 103.588 us; speedup vs baseline: 1.4984x; 1.4984x over previous
//
#include <hip/hip_runtime.h>

// Problem constants (fixed by reference setup_inputs)
#define BATCH 8
#define NPTS  4096   // N == M == 4096
#define KD    64
#define MQ    4      // m-strips: each block walks 1024 cols = 8 tiles of 128
#define WALK  8
#define FINF  3.0e38f

typedef float f32x4 __attribute__((ext_vector_type(4)));
typedef float f32x2 __attribute__((ext_vector_type(2)));
typedef short s16x8 __attribute__((ext_vector_type(8)));

__device__ __forceinline__ unsigned int f2bf(float f) {
  // round-to-nearest-even fp32 -> bf16 (inputs finite)
  unsigned int u = __float_as_uint(f);
  u += 0x7FFFu + ((u >> 16) & 1u);
  return u >> 16;
}

__device__ __forceinline__ void stage16(const void* g, void* l) {
  // async global->LDS, 16B/lane; LDS dst = wave-uniform base + lane*16
  __builtin_amdgcn_global_load_lds((const __attribute__((address_space(1))) void*)g,
                                   (__attribute__((address_space(3))) void*)l, 16, 0, 0);
}

// ---------------------------------------------------------------------------
// Prepass: convert X,Y (fp32 [32768][64]) to bf16 packed (uint [32768][32])
// and compute exact fp32 squared norms. 32 threads per row, 2 floats/thread.
// Also zeroes the reduce-phase counter (stream order makes this race-free).
__global__ __launch_bounds__(256)
void prep_kernel(const float* __restrict__ X, const float* __restrict__ Y,
                 unsigned int* __restrict__ Xbf, unsigned int* __restrict__ Ybf,
                 float* __restrict__ x2, float* __restrict__ y2,
                 unsigned int* __restrict__ counter) {
  int gid = blockIdx.x * 256 + threadIdx.x;
  if (gid == 0) *counter = 0;
  int row = gid >> 5;
  int ki  = gid & 31;
  bool isX = row < BATCH * NPTS;
  int r2 = row & (BATCH * NPTS - 1);
  const float* src = isX ? X : Y;
  f32x2 v = *(const f32x2*)(src + (size_t)r2 * KD + ki * 2);
  float s = v[0] * v[0] + v[1] * v[1];
  #pragma unroll
  for (int m = 16; m >= 1; m >>= 1) s += __shfl_xor(s, m, 64);  // stays in 32-lane half
  unsigned int packed = (f2bf(v[1]) << 16) | f2bf(v[0]);
  (isX ? Xbf : Ybf)[r2 * 32 + ki] = packed;
  if (ki == 0) (isX ? x2 : y2)[r2] = s;
}

// ---------------------------------------------------------------------------
// Main: block = (mq, ntile, b). 128 rows x 1024 cols (8 m-tiles of 128).
// Waves in 2x2: wave tile 64x64 per m-tile.
// X fragments are gathered straight from global in the prologue (read once
// per block; L2/LLC-hot; 8 dwordx4 per wave at 16-rows-x-64B granularity).
// LDS 37KB -> 4 blocks/CU resident (16 waves). 1024 blocks = exactly 4/CU,
// one co-resident set. The j-loop's cross-lane col-reduce is ONE __shfl_xor
// (q-pair reduce); the remaining 4 partials per col go through a padded
// l_credq (stride 132 breaks the x128 bank alias) and are combined in the
// per-tt flush.
// tt-loop is `#pragma unroll 2` (full 8x unroll spilled: 528MB scratch).
// launch_bounds(256,2): 128 VGPR — exactly the 4-blocks/CU cap.
// NOTE (round 6 lesson): do NOT fuse the final reduce into this kernel via
// a last-block ticket — the tail becomes one block doing 64K device-scope
// return-atomics (~400-900ns each, mostly serial) = +60us. The standalone
// reduce gets cross-kernel coherence free at the kernel boundary and uses
// 128 blocks of plain coalesced loads.
__global__ __launch_bounds__(256, 2)
void chamfer_main(const unsigned short* __restrict__ Xbf,
                  const unsigned short* __restrict__ Ybf,
                  const float* __restrict__ x2g, const float* __restrict__ y2g,
                  float* __restrict__ rowpart,   // [MQ][B*N] min over strip cols (sq)
                  float* __restrict__ colpart) { // [32][B*M] min over ntile rows (sq)
  __shared__ __align__(16) unsigned short Ys[2][128 * 64];   // 32 KB
  __shared__ float l_credq[2 * 4 * 132];                     // 4.1 KB, +4 pad vs banks
  __shared__ float l_redf[256];                              // 1 KB

  const int mq = blockIdx.x, ntile = blockIdx.y, b = blockIdx.z;
  const int n0 = ntile * 128;
  const int mbase = mq * (WALK * 128);
  const int t = threadIdx.x, w = t >> 6, lane = t & 63, c = lane & 15, q = lane >> 4;
  const int wr = (w >> 1) * 64, wc = (w & 1) * 64, rg = w >> 1;

  // staging source offset within a 1KB (8-row) block: row=lane>>3, chunk=(lane&7)^(lane>>3)
  const int l8 = lane >> 3;
  const int lane_off = l8 * 128 + (((lane & 7) ^ l8) << 4);

  const unsigned short* Xrow = Xbf + (size_t)(b * NPTS + n0) * KD;  // [128][64] bf16
  const char* Yg0 = (const char*)(Ybf + (size_t)(b * NPTS + mbase) * KD);

  // Prologue: stage Y tile 0 (4 x 1KB per wave)
  #pragma unroll
  for (int k = 0; k < 4; ++k)
    stage16(Yg0 + (k * 32 + w * 8) * 128 + lane_off,
            (char*)Ys[0] + (k * 256 + w * 64) * 16);

  // X fragments straight from global (once per block). Lane (q,c) reads rows
  // wr+i*16+c, k-chunk (ks*4+q)*8 — per instr: 16 rows x 64B segments. 32 VGPRs.
  s16x8 xf[4][2];
  #pragma unroll
  for (int i = 0; i < 4; ++i)
    #pragma unroll
    for (int ks = 0; ks < 2; ++ks)
      xf[i][ks] = *(const s16x8*)&Xrow[(size_t)(wr + i * 16 + c) * KD + (ks * 4 + q) * 8];

  // x2 fragment (rows wr + i*16 + q*4 + r), fp32, L2-hot. 16 VGPRs.
  const float* x2b = x2g + b * NPTS + n0;
  f32x4 x2r[4];
  #pragma unroll
  for (int i = 0; i < 4; ++i) x2r[i] = *(const f32x4*)(x2b + wr + i * 16 + q * 4);

  __syncthreads();  // drains the Y0 global_load_lds (vmcnt 0 at barrier)

  float rm[4][4];
  #pragma unroll
  for (int i = 0; i < 4; ++i)
    #pragma unroll
    for (int r = 0; r < 4; ++r) rm[i][r] = FINF;

  const int cx = c & 7;
  const float* y2b = y2g + b * NPTS + mbase;
  float* colrow = colpart + (size_t)(ntile * 8 + b) * NPTS + mbase;
  const f32x4 zacc = {0.f, 0.f, 0.f, 0.f};

  #pragma unroll 2
  for (int tt = 0; tt < WALK; ++tt) {
    const unsigned short* cur = Ys[tt & 1];

    // y2 for this wave's 4 col groups — issue global loads first (async).
    float y2c[4];
    #pragma unroll
    for (int j = 0; j < 4; ++j) y2c[j] = y2b[tt * 128 + wc + j * 16 + c];

    if (tt < WALK - 1) {  // async-prefetch next Y tile into the other buffer
      const char* Ygt = Yg0 + (size_t)(tt + 1) * 128 * 128;
      unsigned short* nb = Ys[(tt + 1) & 1];
      #pragma unroll
      for (int k = 0; k < 4; ++k)
        stage16(Ygt + (k * 32 + w * 8) * 128 + lane_off,
                (char*)nb + (k * 256 + w * 64) * 16);
    }

    // Flush previous tile's col-mins (combine 4 q-pair/rowgroup partials,
    // add y2, store). l_credq[pb] was written before the barrier that ended
    // tt-1 -> visible; it is rewritten only after the barrier ending THIS tt.
    if (tt > 0 && t < 128) {
      int pt = tt - 1, pb = pt & 1;
      float v = fminf(fminf(l_credq[(pb * 4 + 0) * 132 + t], l_credq[(pb * 4 + 1) * 132 + t]),
                      fminf(l_credq[(pb * 4 + 2) * 132 + t], l_credq[(pb * 4 + 3) * 132 + t]));
      colrow[pt * 128 + t] = v + y2b[pt * 128 + t];
    }

    float cmj[4];
    #pragma unroll
    for (int j = 0; j < 4; ++j) {
      const unsigned short* yrow = &cur[(wc + j * 16 + c) * 64];
      s16x8 yf0 = *(const s16x8*)&yrow[(q ^ cx) << 3];
      s16x8 yf1 = *(const s16x8*)&yrow[((4 + q) ^ cx) << 3];
      f32x4 acc[4];
      #pragma unroll
      for (int i = 0; i < 4; ++i) {
        f32x4 a0 = __builtin_amdgcn_mfma_f32_16x16x32_bf16(xf[i][0], yf0, zacc, 0, 0, 0);
        acc[i] = __builtin_amdgcn_mfma_f32_16x16x32_bf16(xf[i][1], yf1, a0, 0, 0, 0);
      }
      float cm = FINF;
      #pragma unroll
      for (int i = 0; i < 4; ++i)
        #pragma unroll
        for (int r = 0; r < 4; ++r) {
          float v = acc[i][r];
          rm[i][r] = fminf(rm[i][r], fmaf(-2.f, v, y2c[j]));
          cm = fminf(cm, fmaf(-2.f, v, x2r[i][r]));
        }
      // ONE cross-lane step: combine q-pairs {0,1} and {2,3}
      cm = fminf(cm, __shfl_xor(cm, 16, 64));
      cmj[j] = cm;
    }
    // Each lane stores 2 of the (q-half, j) partials: q&1 picks the j-pair,
    // q>>1 picks the row-half slot. Addr stride 132 breaks the x128 bank alias.
    {
      int s = rg * 2 + (q >> 1);
      int jA = (q & 1) * 2;
      float sA = (q & 1) ? cmj[2] : cmj[0];
      float sB = (q & 1) ? cmj[3] : cmj[1];
      float* dst = &l_credq[((tt & 1) * 4 + s) * 132 + wc + c];
      dst[jA * 16]      = sA;
      dst[jA * 16 + 16] = sB;
    }

    __syncthreads();  // buffer swap barrier (prefetch had MFMA+epilogue to land)
  }

  // Row-min: reduce over the 16 c-lanes within each q-group...
  #pragma unroll
  for (int msk = 1; msk <= 8; msk <<= 1)
    #pragma unroll
    for (int i = 0; i < 4; ++i)
      #pragma unroll
      for (int r = 0; r < 4; ++r)
        rm[i][r] = fminf(rm[i][r], __shfl_xor(rm[i][r], msk, 64));
  // ...then store per-wave row-mins to LDS (literal indices only).
  if (c == 0) {
    #pragma unroll
    for (int i = 0; i < 4; ++i) {
      f32x4 v = {rm[i][0], rm[i][1], rm[i][2], rm[i][3]};
      *(f32x4*)&l_redf[w * 64 + i * 16 + q * 4] = v;
    }
  }
  __syncthreads();

  if (t < 128) {
    // flush the final tile's col-mins (last loop barrier made them visible)
    {
      int pt = WALK - 1, pb = pt & 1;
      float v = fminf(fminf(l_credq[(pb * 4 + 0) * 132 + t], l_credq[(pb * 4 + 1) * 132 + t]),
                      fminf(l_credq[(pb * 4 + 2) * 132 + t], l_credq[(pb * 4 + 3) * 132 + t]));
      colrow[pt * 128 + t] = v + y2b[pt * 128 + t];
    }
    // combine the 2 col-group waves of each row group, add x2, store
    int g = t >> 6, lr = t & 63;
    float v = fminf(l_redf[(g * 2) * 64 + lr], l_redf[(g * 2 + 1) * 64 + lr]);
    rowpart[mq * (BATCH * NPTS) + b * NPTS + n0 + t] = v + x2b[t];
  }
}

// ---------------------------------------------------------------------------
// Final: min over partials, sqrt, mean — self-finalizing (no memset, no 4th
// stream op). 128 blocks; the last block (device-scope ticket) sums the 128
// block partials and writes the scalar output.
__global__ __launch_bounds__(256)
void reduce_kernel(const float* __restrict__ rowpart, const float* __restrict__ colpart,
                   float* __restrict__ partials, unsigned int* __restrict__ counter,
                   float* __restrict__ out) {
  int i = blockIdx.x * 256 + threadIdx.x;
  const int TOT = BATCH * NPTS;
  float rv = FINF;
  #pragma unroll
  for (int s = 0; s < MQ; ++s) rv = fminf(rv, rowpart[s * TOT + i]);
  float s0 = sqrtf(fmaxf(rv, 0.f));
  float cv = FINF;
  #pragma unroll
  for (int nt = 0; nt < 32; ++nt) cv = fminf(cv, colpart[nt * TOT + i]);
  s0 += sqrtf(fmaxf(cv, 0.f));
  #pragma unroll
  for (int m = 32; m >= 1; m >>= 1) s0 += __shfl_xor(s0, m, 64);
  __shared__ float wsum[4];
  if ((threadIdx.x & 63) == 0) wsum[threadIdx.x >> 6] = s0;
  __syncthreads();

  if (threadIdx.x < 64) {  // wave 0 publishes the block partial, then maybe finalizes
    unsigned int ticket = 0;
    if (threadIdx.x == 0) {
      float bsum = wsum[0] + wsum[1] + wsum[2] + wsum[3];
      atomicExch(&partials[blockIdx.x], bsum);  // device-scope visible store
      __threadfence();
      ticket = atomicAdd(counter, 1);
    }
    ticket = __shfl(ticket, 0, 64);
    if (ticket == 127) {  // all 128 partials published
      float v = atomicAdd(&partials[threadIdx.x], 0.0f) +
                atomicAdd(&partials[threadIdx.x + 64], 0.0f);
      #pragma unroll
      for (int m = 32; m >= 1; m >>= 1) v += __shfl_xor(v, m, 64);
      if (threadIdx.x == 0) out[0] = v * (1.0f / (float)TOT);
    }
  }
}

// ---------------------------------------------------------------------------
extern "C" void kernel_launch(void* const* d_in, const int* in_sizes, int n_in,
                              void* d_out, int out_size, void* d_ws, size_t ws_size,
                              hipStream_t stream) {
  const float* X = (const float*)d_in[0];  // [B, N, 64] fp32
  const float* Y = (const float*)d_in[1];  // [B, M, 64] fp32
  float* out = (float*)d_out;

  // Workspace layout (bytes):
  //   Xbf 4MB | Ybf 4MB | x2 128KB | y2 128KB | rowpart 1MB (uses 512KB)
  //   | colpart 4MB | partials 512B | counter 4B
  char* ws = (char*)d_ws;
  unsigned int* Xbf = (unsigned int*)ws;                       // packed bf16 pairs
  unsigned int* Ybf = (unsigned int*)(ws + (4u << 20));
  float* x2 = (float*)(ws + (8u << 20));
  float* y2 = (float*)(ws + (8u << 20) + (128u << 10));
  float* rowpart = (float*)(ws + (8u << 20) + (256u << 10));
  float* colpart = (float*)(ws + (9u << 20) + (256u << 10));
  float* partials = (float*)(ws + (13u << 20) + (256u << 10));
  unsigned int* counter = (unsigned int*)(partials + 128);

  // Prepass: both inputs, 32 threads/row. Also zeroes `counter`.
  prep_kernel<<<dim3(2 * BATCH * NPTS * 32 / 256), dim3(256), 0, stream>>>(
      X, Y, Xbf, Ybf, x2, y2, counter);

  // Main: (mq=4, ntile=32, b=8) = 1024 blocks, 4 resident/CU (LDS 37KB).
  chamfer_main<<<dim3(MQ, 32, 8), dim3(256), 0, stream>>>(
      (const unsigned short*)Xbf, (const unsigned short*)Ybf, x2, y2, rowpart, colpart);

  // Final min/sqrt/mean (self-finalizing via ticket).
  reduce_kernel<<<dim3(BATCH * NPTS / 256), dim3(256), 0, stream>>>(
      rowpart, colpart, partials, counter, out);
}